// Round 2
// baseline (379.056 us; speedup 1.0000x reference)
//
#include <hip/hip_runtime.h>
#include <stdint.h>

#define B_   4
#define C_   256
#define W_   4096
#define DQK_ 32

typedef short bf16x8 __attribute__((ext_vector_type(8)));
typedef float f32x4  __attribute__((ext_vector_type(4)));

__device__ __forceinline__ float fexp2f(float x){
#if __has_builtin(__builtin_amdgcn_exp2f)
  return __builtin_amdgcn_exp2f(x);
#else
  return exp2f(x);
#endif
}
__device__ __forceinline__ float frcpf(float x){
#if __has_builtin(__builtin_amdgcn_rcpf)
  return __builtin_amdgcn_rcpf(x);
#else
  return 1.0f / x;
#endif
}
__device__ __forceinline__ unsigned short bf16rn(float f){
  union { float f; uint32_t u; } v; v.f = f;
  uint32_t u = v.u;
  u += 0x7FFFu + ((u >> 16) & 1u);
  return (unsigned short)(u >> 16);
}

// ---------------------------------------------------------------------------
// Kernel 1: projections q = wq@x0+bq, k = (wk@x1+bk)*scale*log2e  -> bf16
//           qT/kT layout [B][W][32] row-major, plus x0 -> bf16 (x0b [B][C][W]).
// grid (64, 4), block 512: 8 waves, wave cq handles c-range cq*32..+32.
// ---------------------------------------------------------------------------
__global__ __launch_bounds__(512) void sa_prep(
    const float* __restrict__ x0, const float* __restrict__ x1,
    const float* __restrict__ wq, const float* __restrict__ bq,
    const float* __restrict__ wk, const float* __restrict__ bk,
    unsigned short* __restrict__ qT, unsigned short* __restrict__ kT,
    unsigned short* __restrict__ x0b)
{
  const int b    = blockIdx.y;
  const int lane = threadIdx.x & 63;
  const int cq   = threadIdx.x >> 6;           // 0..7
  const int w    = blockIdx.x * 64 + lane;
  const size_t bw = (size_t)b * ((size_t)C_ * W_) + w;

  float accq[DQK_], acck[DQK_];
  #pragma unroll
  for (int d = 0; d < DQK_; ++d){ accq[d] = 0.f; acck[d] = 0.f; }

  const int c0 = cq * 32;
  #pragma unroll
  for (int i = 0; i < 32; ++i){
    const int c = c0 + i;
    const size_t off = bw + (size_t)c * W_;
    const float v0 = x0[off];
    const float v1 = x1[off];
    x0b[off] = bf16rn(v0);
    #pragma unroll
    for (int d = 0; d < DQK_; ++d){
      accq[d] = fmaf(wq[d * C_ + c], v0, accq[d]);
      acck[d] = fmaf(wk[d * C_ + c], v1, acck[d]);
    }
  }

  __shared__ float red[8][64][DQK_ + 1];
  #pragma unroll
  for (int d = 0; d < DQK_; ++d) red[cq][lane][d] = accq[d];
  __syncthreads();
  {
    // all 512 threads: thread (cq,lane) packs d-range cq*4..+4 for position w=lane
    const int d0 = cq * 4;
    float s[4];
    #pragma unroll
    for (int j = 0; j < 4; ++j){
      float t = bq[d0 + j];
      #pragma unroll
      for (int w8 = 0; w8 < 8; ++w8) t += red[w8][lane][d0 + j];
      s[j] = t;
    }
    uint2 pk;
    pk.x = (uint32_t)bf16rn(s[0]) | ((uint32_t)bf16rn(s[1]) << 16);
    pk.y = (uint32_t)bf16rn(s[2]) | ((uint32_t)bf16rn(s[3]) << 16);
    *(uint2*)(qT + ((size_t)b * W_ + (size_t)blockIdx.x * 64 + lane) * DQK_ + d0) = pk;
  }
  __syncthreads();
  #pragma unroll
  for (int d = 0; d < DQK_; ++d) red[cq][lane][d] = acck[d];
  __syncthreads();
  {
    const float SCL = 0.0625f * 1.44269504088896340736f; // 1/sqrt(256) * log2(e)
    const int d0 = cq * 4;
    float s[4];
    #pragma unroll
    for (int j = 0; j < 4; ++j){
      float t = bk[d0 + j];
      #pragma unroll
      for (int w8 = 0; w8 < 8; ++w8) t += red[w8][lane][d0 + j];
      s[j] = t * SCL;
    }
    uint2 pk;
    pk.x = (uint32_t)bf16rn(s[0]) | ((uint32_t)bf16rn(s[1]) << 16);
    pk.y = (uint32_t)bf16rn(s[2]) | ((uint32_t)bf16rn(s[3]) << 16);
    *(uint2*)(kT + ((size_t)b * W_ + (size_t)blockIdx.x * 64 + lane) * DQK_ + d0) = pk;
  }
}

// ---------------------------------------------------------------------------
// Kernel 2: per (b, 16-row m-tile): 4 waves split the 4096 columns (1024 each).
// Pass1: sum of exp2(e) (no max subtraction: |e*log2e| << 125, overflow
// impossible), LDS-combined across waves. Pass2: recompute e, write f32 att,
// PV partial per wave, LDS cross-wave reduce + epilogue.
// grid 1024 (XCD-swizzled: batch b -> XCDs {2b,2b+1}), block 256 (4 waves).
// ---------------------------------------------------------------------------
__global__ __launch_bounds__(256) void sa_attn(
    const unsigned short* __restrict__ qT, const unsigned short* __restrict__ kT,
    const unsigned short* __restrict__ x0b, const float* __restrict__ x1,
    const float* __restrict__ gamma,
    float* __restrict__ out, float* __restrict__ att)
{
  const int lb = blockIdx.x;
  const int b = (lb & 7) >> 1;                       // batch -> XCD pair
  const int mtile = ((lb >> 3) << 1) | (lb & 1);     // 0..255
  const int lane = threadIdx.x & 63;
  const int wid = threadIdx.x >> 6;                  // 0..3
  const int lr = lane & 15;
  const int lg = lane >> 4;
  const int m0 = mtile * 16;
  const int nbase = wid * 1024;

  // A-frag (energy): kT rows m0+lr, k-slice lg*8..+8 (16B contiguous)
  const bf16x8 kfrag = *(const bf16x8*)(kT + ((size_t)b * W_ + m0 + lr) * DQK_ + (size_t)lg * 8);
  const unsigned short* qb = qT + (size_t)b * W_ * DQK_;

  // ---- pass 1: per-lane sum of exp2 over this wave's 1024-column slice ----
  float ps[4] = {0.f, 0.f, 0.f, 0.f};
  for (int i = 0; i < 32; ++i){
    const int n0 = nbase + i * 32;
    bf16x8 q0 = *(const bf16x8*)(qb + (size_t)(n0 + lr) * DQK_ + (size_t)lg * 8);
    bf16x8 q1 = *(const bf16x8*)(qb + (size_t)(n0 + 16 + lr) * DQK_ + (size_t)lg * 8);
    f32x4 e0 = __builtin_amdgcn_mfma_f32_16x16x32_bf16(kfrag, q0, (f32x4){0.f,0.f,0.f,0.f}, 0, 0, 0);
    f32x4 e1 = __builtin_amdgcn_mfma_f32_16x16x32_bf16(kfrag, q1, (f32x4){0.f,0.f,0.f,0.f}, 0, 0, 0);
    #pragma unroll
    for (int r = 0; r < 4; ++r)
      ps[r] += fexp2f(e0[r]) + fexp2f(e1[r]);
  }
  // combine across the 16 lanes (lr dimension) sharing each row
  #pragma unroll
  for (int mask = 1; mask <= 8; mask <<= 1){
    #pragma unroll
    for (int r = 0; r < 4; ++r) ps[r] += __shfl_xor(ps[r], mask);
  }
  // combine across the 4 waves (each covered a different column slice)
  __shared__ float ssum[4][16];
  if (lr == 0){
    #pragma unroll
    for (int r = 0; r < 4; ++r) ssum[wid][lg * 4 + r] = ps[r];
  }
  __syncthreads();
  float invS[4];
  #pragma unroll
  for (int r = 0; r < 4; ++r){
    const int row = lg * 4 + r;
    invS[r] = frcpf(ssum[0][row] + ssum[1][row] + ssum[2][row] + ssum[3][row]);
  }

  // ---- pass 2: recompute energy, write attention, PV partial accumulate ----
  __shared__ __align__(16) unsigned short Plds[4][16][40]; // per-wave P tile, row pad 80B
  unsigned short* aw = &Plds[wid][0][0];

  f32x4 acc[16];
  #pragma unroll
  for (int ct = 0; ct < 16; ++ct) acc[ct] = (f32x4){0.f,0.f,0.f,0.f};

  const unsigned short* xb = x0b + (size_t)b * C_ * W_;
  float* attb = att + ((size_t)b * W_ + m0) * W_;
  float* arow[4];
  #pragma unroll
  for (int r = 0; r < 4; ++r) arow[r] = attb + (size_t)(lg * 4 + r) * W_ + lr;
  const unsigned short* xrow = xb + (size_t)lr * W_ + (size_t)lg * 8;

  for (int i = 0; i < 32; ++i){
    const int n0 = nbase + i * 32;
    bf16x8 q0 = *(const bf16x8*)(qb + (size_t)(n0 + lr) * DQK_ + (size_t)lg * 8);
    bf16x8 q1 = *(const bf16x8*)(qb + (size_t)(n0 + 16 + lr) * DQK_ + (size_t)lg * 8);
    f32x4 e0 = __builtin_amdgcn_mfma_f32_16x16x32_bf16(kfrag, q0, (f32x4){0.f,0.f,0.f,0.f}, 0, 0, 0);
    f32x4 e1 = __builtin_amdgcn_mfma_f32_16x16x32_bf16(kfrag, q1, (f32x4){0.f,0.f,0.f,0.f}, 0, 0, 0);
    #pragma unroll
    for (int r = 0; r < 4; ++r){
      const int row = lg * 4 + r;
      float p0 = fexp2f(e0[r]) * invS[r];
      float p1 = fexp2f(e1[r]) * invS[r];
      arow[r][n0]      = p0;
      arow[r][n0 + 16] = p1;
      aw[row * 40 + lr]      = bf16rn(p0);
      aw[row * 40 + 16 + lr] = bf16rn(p1);
    }
    // B-frag (PV): P[m=lr][n-slice lg*8..+8]
    bf16x8 afrag = *(const bf16x8*)(aw + lr * 40 + lg * 8);
    #pragma unroll
    for (int ct = 0; ct < 16; ++ct){
      bf16x8 xf = *(const bf16x8*)(xrow + (size_t)(ct * 16) * W_ + n0);
      acc[ct] = __builtin_amdgcn_mfma_f32_16x16x32_bf16(xf, afrag, acc[ct], 0, 0, 0);
    }
  }

  // ---- cross-wave PV reduce (2 rounds x 8 c-tiles) + epilogue ----
  __shared__ float red2[4][8][64][4];                // 32 KB
  const float g = gamma[0];
  const float* x1b = x1 + (size_t)b * C_ * W_;
  float* outb = out + (size_t)b * C_ * W_;
  #pragma unroll
  for (int round = 0; round < 2; ++round){
    __syncthreads();
    #pragma unroll
    for (int ctl = 0; ctl < 8; ++ctl)
      *(f32x4*)&red2[wid][ctl][lane][0] = acc[round * 8 + ctl];
    __syncthreads();
    #pragma unroll
    for (int j = 0; j < 2; ++j){
      const int ctl = wid * 2 + j;
      const int ct = round * 8 + ctl;
      f32x4 s = *(const f32x4*)&red2[0][ctl][lane][0];
      #pragma unroll
      for (int w4 = 1; w4 < 4; ++w4) s += *(const f32x4*)&red2[w4][ctl][lane][0];
      #pragma unroll
      for (int r = 0; r < 4; ++r){
        const int c = ct * 16 + lg * 4 + r;
        const size_t idx = (size_t)c * W_ + m0 + lr;
        outb[idx] = fmaf(g, s[r], x1b[idx]);
      }
    }
  }
}

extern "C" void kernel_launch(void* const* d_in, const int* in_sizes, int n_in,
                              void* d_out, int out_size, void* d_ws, size_t ws_size,
                              hipStream_t stream)
{
  const float* x0    = (const float*)d_in[0];
  const float* x1    = (const float*)d_in[1];
  const float* wq    = (const float*)d_in[2];
  const float* bq    = (const float*)d_in[3];
  const float* wk    = (const float*)d_in[4];
  const float* bk    = (const float*)d_in[5];
  const float* gamma = (const float*)d_in[6];

  unsigned short* qT  = (unsigned short*)d_ws;                 // [B][W][32] bf16, 1 MB
  unsigned short* kT  = qT + (size_t)B_ * W_ * DQK_;           // 1 MB
  unsigned short* x0b = kT + (size_t)B_ * W_ * DQK_;           // [B][C][W] bf16, 8 MB

  float* out = (float*)d_out;                                  // [B][C][W]
  float* att = out + (size_t)B_ * C_ * W_;                     // [B][W][W]

  sa_prep<<<dim3(64, 4), 512, 0, stream>>>(x0, x1, wq, bq, wk, bk, qT, kT, x0b);
  sa_attn<<<1024, 256, 0, stream>>>(qT, kT, x0b, x1, gamma, out, att);
}